// Round 10
// baseline (126.497 us; speedup 1.0000x reference)
//
#include <hip/hip_runtime.h>

// Depthwise Gaussian blur K=121, replicate pad, separable, fp32. FUSED.
// R17 = decisive decomposition of the R10-12 traffic mystery:
//   V phase   : R16 verbatim (clamped, 3-buffer load-ahead-by-2) -- the
//               config with PROVEN clean traffic (FETCH 12.35/WRITE 24.6MB).
//               NO interior branch: all traffic-inflated rounds (R10/11/12,
//               FETCH 2x WRITE 2.7-13x) shared the interior-V-branch;
//               R13 removed it and traffic snapped clean. R12's store
//               addresses were per-instruction identical to R9's yet
//               inflated -> branch is the prime suspect, not the store.
//   H phase   : R10's contiguous 16-col span per lane. 18 group loads =
//               36 b128/lane vs 76. Conflict cycles scale with read count
//               at constant per-read rate (R16: 76->8.6M; R10: 36->3.6M),
//               ~14us/CU of LDS-pipe time -> halved.
//   store     : R12's verified xor-16 lane exchange -> R9's paired
//               32B-stride float4 pattern (only write-combine-clean form).
// Kept: scalar pre-normalized weights from d_ws, XOR-swizzle LDS (ROWF
// 672), XCD swizzle, launch_bounds(256,6) / 6+ blocks/CU.

#define HH    512
#define WW    512
#define PLANE (512 * 512)
#define NIMG  24
#define ROWF  672                    // 168 16B-units/row, swizzle-bijective

// ---- pre-kernel: 128 normalized 1-D taps -> d_ws --------------------------
__global__ void wk_prep(const float* __restrict__ sigma,
                        float* __restrict__ wg) {
    const int tid = threadIdx.x;                     // 128 threads, 1 block
    const float s = sigma[0] * 8.0f + 16.0f;
    const float inv2v = 1.0f / (2.0f * s * s);
    float sum = 0.0f;
    #pragma unroll
    for (int k = 0; k <= 120; ++k) {
        const float c = (float)k - 60.0f;
        sum += __expf(-c * c * inv2v);
    }
    float g = 0.0f;
    if (tid < 121) {
        const float c = (float)tid - 60.0f;
        g = __expf(-c * c * inv2v);
    }
    wg[tid] = g / sum;               // taps 121..127 exactly 0
}

// dword offset within an LDS row for padded column `col` (swizzled)
__device__ __forceinline__ int swz_off(int col) {
    const int u = col >> 2;
    return ((u ^ ((u >> 3) & 7)) << 2) + (col & 3);
}

// Vertical octet, pipelined: A=X_t (rows base..), B=X_{t+1}; prefetch
// C=X_{t+2} (rows base+16.., clamped) issued BEFORE the FMAs.
// vac[j] += w[8KO+ki] * row[base+ki+j], idx=ki+j in [0,14] -> A/B only.
#define V_OCT_P(A, B, C, KO)                                              \
    { _Pragma("unroll")                                                   \
      for (int ki = 0; ki < 8; ++ki) {                                    \
          int rr = r0 - 44 + (KO) * 8 + ki;                               \
          rr = rr < 0 ? 0 : (rr > HH - 1 ? HH - 1 : rr);                  \
          C[ki] = *(const float2*)&src[(size_t)rr * WW];                  \
      }                                                                   \
      *(float4*)&wq[0] = *(const float4*)&wg[(KO) * 8];                   \
      *(float4*)&wq[4] = *(const float4*)&wg[(KO) * 8 + 4];               \
      _Pragma("unroll")                                                   \
      for (int ki = 0; ki < 8; ++ki) {                                    \
          const float wk = wq[ki];                                        \
          _Pragma("unroll")                                               \
          for (int j = 0; j < 8; ++j) {                                   \
              const int idx = ki + j;                                     \
              const float2 v = (idx < 8) ? A[idx] : B[idx - 8];           \
              vac[j].x += wk * v.x; vac[j].y += wk * v.y;                 \
          }                                                               \
      }                                                                   \
    }

// Final octet (KO=15): no prefetch; taps 121..127 are zero.
#define V_OCT_NP(A, B, KO)                                                \
    { *(float4*)&wq[0] = *(const float4*)&wg[(KO) * 8];                   \
      *(float4*)&wq[4] = *(const float4*)&wg[(KO) * 8 + 4];               \
      _Pragma("unroll")                                                   \
      for (int ki = 0; ki < 8; ++ki) {                                    \
          const float wk = wq[ki];                                        \
          _Pragma("unroll")                                               \
          for (int j = 0; j < 8; ++j) {                                   \
              const int idx = ki + j;                                     \
              const float2 v = (idx < 8) ? A[idx] : B[idx - 8];           \
              vac[j].x += wk * v.x; vac[j].y += wk * v.y;                 \
          }                                                               \
      }                                                                   \
    }

// Load group G (8 floats): phys(2G+1) = phys(2G)^1 -> one addr calc / 2 b128
#define LOADG(D, G)                                                       \
    { const int u_  = 2 * (G);                                            \
      const int o1_ = (u_ ^ ((u_ >> 3) & 7)) << 2;                        \
      *(float4*)&D[0] = *(const float4*)(bs + o1_);                       \
      *(float4*)&D[4] = *(const float4*)(bs + (o1_ ^ 4)); }

// One octet over a contiguous 16-col span; window A0..A2 (idx<=22), A3 pre.
#define H_OCT16(A0, A1, A2, A3, KO)                                       \
    { LOADG(A3, 2 * L + (KO) + 3)                                         \
      *(float4*)&wq[0] = *(const float4*)&wg[(KO) * 8];                   \
      *(float4*)&wq[4] = *(const float4*)&wg[(KO) * 8 + 4];               \
      _Pragma("unroll")                                                   \
      for (int ki = 0; ki < 8; ++ki) {                                    \
          const float wk = wq[ki];                                        \
          _Pragma("unroll")                                               \
          for (int j = 0; j < 16; ++j) {                                  \
              const int idx = ki + j;                                     \
              const float v = (idx < 8) ? A0[idx]                         \
                            : (idx < 16) ? A1[idx - 8] : A2[idx - 16];    \
              acc[j] += wk * v;                                           \
          }                                                               \
      }                                                                   \
    }

// Final octet: no prefetch (window = groups 15..17, all resident)
#define H_OCT16_NP(A0, A1, A2, A3, KO)                                    \
    { *(float4*)&wq[0] = *(const float4*)&wg[(KO) * 8];                   \
      *(float4*)&wq[4] = *(const float4*)&wg[(KO) * 8 + 4];               \
      _Pragma("unroll")                                                   \
      for (int ki = 0; ki < 8; ++ki) {                                    \
          const float wk = wq[ki];                                        \
          _Pragma("unroll")                                               \
          for (int j = 0; j < 16; ++j) {                                  \
              const int idx = ki + j;                                     \
              const float v = (idx < 8) ? A0[idx]                         \
                            : (idx < 16) ? A1[idx - 8] : A2[idx - 16];    \
              acc[j] += wk * v;                                           \
          }                                                               \
      }                                                                   \
    }

__global__ __launch_bounds__(256, 6) void blur_fused(
        const float* __restrict__ x, const float* __restrict__ wg,
        float* __restrict__ out) {
    __shared__ float sm[8 * ROWF];                   // 21504 B
    const int tid = threadIdx.x;

    // XCD swizzle: linear id -> contiguous 192-tile span per XCD (%8 rr).
    const int lid   = blockIdx.x + gridDim.x * blockIdx.y;   // 0..1535
    const int tile  = (lid & 7) * 192 + (lid >> 3);
    const int r0    = (tile & 63) * 8;               // output rows r0..r0+7
    const int plane = tile >> 6;

    const int c0 = tid * 2;                          // this thread's 2 cols
    const float* __restrict__ src = x + (size_t)plane * PLANE + c0;

    // ---- vertical: 8 rows x 2 cols, 3-buffer load-ahead-by-2 pipeline ----
    float2 w0[8], w1[8], w2[8], vac[8];
    float  wq[8];
    #pragma unroll
    for (int m = 0; m < 8; ++m) {                    // X_0: rows r0-60..r0-53
        int rr = r0 - 60 + m;
        rr = rr < 0 ? 0 : rr;
        w0[m] = *(const float2*)&src[(size_t)rr * WW];
    }
    #pragma unroll
    for (int m = 0; m < 8; ++m) {                    // X_1: rows r0-52..r0-45
        int rr = r0 - 52 + m;
        rr = rr < 0 ? 0 : rr;
        w1[m] = *(const float2*)&src[(size_t)rr * WW];
    }
    #pragma unroll
    for (int j = 0; j < 8; ++j) vac[j] = make_float2(0.f, 0.f);

    #pragma unroll 1
    for (int ko = 0; ko < 15; ko += 3) {             // octets 0..14, period-3
        V_OCT_P(w0, w1, w2, ko)
        V_OCT_P(w1, w2, w0, ko + 1)
        V_OCT_P(w2, w0, w1, ko + 2)
    }
    V_OCT_NP(w0, w1, 15)                             // octet 15, no prefetch

    // write intermediate at halo offset +60 (swizzled; float2 stays in-unit)
    {
        const int off = swz_off(c0 + 60);            // col even -> within-unit
        #pragma unroll
        for (int j = 0; j < 8; ++j)
            *(float2*)&sm[j * ROWF + off] = vac[j];
    }
    __syncthreads();

    // ---- halo: idx 0..59 <- 60; 572..647 <- 571; zero 648..655 -----------
    if (tid < 36) {
        const int p = (tid < 15) ? tid * 4
                    : (tid < 34) ? 572 + (tid - 15) * 4
                                 : 648 + (tid - 34) * 4;
        const int u   = p >> 2;
        const int off = (u ^ ((u >> 3) & 7)) << 2;   // 16B-aligned
        const int soff = (tid < 15) ? swz_off(60) : swz_off(571);
        #pragma unroll
        for (int r8 = 0; r8 < 8; ++r8) {
            const float v = (tid < 34) ? sm[r8 * ROWF + soff] : 0.0f;
            *(float4*)&sm[r8 * ROWF + off] = make_float4(v, v, v, v);
        }
    }
    __syncthreads();

    // ---- horizontal: ONE contiguous 16-col span per lane (18 groups) -----
    const int r = tid >> 5;                          // 0..7
    const int L = tid & 31;                          // span cols 16L..16L+15
    const float* __restrict__ bs = sm + r * ROWF;

    float a0[8], a1[8], a2[8], a3[8];
    float acc[16];
    #pragma unroll
    for (int j = 0; j < 16; ++j) acc[j] = 0.0f;

    LOADG(a0, 2 * L)
    LOADG(a1, 2 * L + 1)
    LOADG(a2, 2 * L + 2)

    #pragma unroll 1
    for (int ko = 0; ko < 12; ko += 4) {
        H_OCT16(a0, a1, a2, a3, ko)
        H_OCT16(a1, a2, a3, a0, ko + 1)
        H_OCT16(a2, a3, a0, a1, ko + 2)
        H_OCT16(a3, a0, a1, a2, ko + 3)
    }
    H_OCT16   (a0, a1, a2, a3, 12)
    H_OCT16   (a1, a2, a3, a0, 13)
    H_OCT16   (a2, a3, a0, a1, 14)
    H_OCT16_NP(a3, a0, a1, a2, 15)

    // ---- store: xor-16 lane exchange -> paired 32B-stride pattern --------
    // sel=0 lane: keeps cols 16L..+7 (acc[0..7]), receives partner's
    // +256..+263; sel=1: receives 16(L&15)+8..+15, keeps +264..+271.
    {
        const int sel = (L >> 4) & 1;
        float blk1[8], blk2[8];
        #pragma unroll
        for (int j = 0; j < 8; ++j) {
            const float send = sel ? acc[j] : acc[j + 8];
            const float recv = __shfl_xor(send, 16, 64);
            blk1[j] = sel ? recv : acc[j];
            blk2[j] = sel ? acc[j + 8] : recv;
        }
        float* __restrict__ dst = out + (size_t)plane * PLANE
                                      + (size_t)(r0 + r) * WW
                                      + 16 * (L & 15) + sel * 8;
        *(float4*)(dst)       = make_float4(blk1[0], blk1[1], blk1[2], blk1[3]);
        *(float4*)(dst + 4)   = make_float4(blk1[4], blk1[5], blk1[6], blk1[7]);
        *(float4*)(dst + 256) = make_float4(blk2[0], blk2[1], blk2[2], blk2[3]);
        *(float4*)(dst + 260) = make_float4(blk2[4], blk2[5], blk2[6], blk2[7]);
    }
}

extern "C" void kernel_launch(void* const* d_in, const int* in_sizes, int n_in,
                              void* d_out, int out_size, void* d_ws, size_t ws_size,
                              hipStream_t stream) {
    const float* x     = (const float*)d_in[0];
    const float* sigma = (const float*)d_in[1];
    float* out = (float*)d_out;
    float* wg  = (float*)d_ws;                       // 512 B of workspace
    wk_prep<<<dim3(1), dim3(128), 0, stream>>>(sigma, wg);
    blur_fused<<<dim3(HH / 8, NIMG), dim3(256), 0, stream>>>(x, wg, out);
}

// Round 11
// 125.622 us; speedup vs baseline: 1.0070x; 1.0070x over previous
//
#include <hip/hip_runtime.h>

// Depthwise Gaussian blur K=121, replicate pad, separable, fp32. FUSED.
// R18: test of the lane-order-sensitive write-coalescer theory.
// All dirty rounds (R10/11/12/17, WRITE 2.7-13x) broke adjacent-lane
// contiguity in stores; all clean rounds (R9/13/16) had lane L -> base +
// 32B*L monotone. R17 proved address SETS equal is NOT enough.
// Fix: keep the 16-col H compute (36 b128/lane, conflicts 1.7M vs 8.6M)
// but permute the span assignment: lane L computes span sigma(L) =
// (L>>1) + 16*(L&1), then ONE xor-1 exchange (8 shuffles: even lane
// sends acc[8..15], odd sends acc[0..7]) lands lane L with exactly cols
// 8L..8L+7 and 8L+256..+263 -> store is byte-for-byte, lane-for-lane
// identical to R9/R13/R16's proven pattern. LDS read sets per instr are
// permutation-invariant -> conflicts stay at the 16-col floor.
// Kept: R16 V phase (3-buffer load-ahead-2, clamped), scalar
// pre-normalized weights from d_ws, XOR-swizzle LDS (ROWF 672),
// XCD swizzle, launch_bounds(256,6).

#define HH    512
#define WW    512
#define PLANE (512 * 512)
#define NIMG  24
#define ROWF  672                    // 168 16B-units/row, swizzle-bijective

// ---- pre-kernel: 128 normalized 1-D taps -> d_ws --------------------------
__global__ void wk_prep(const float* __restrict__ sigma,
                        float* __restrict__ wg) {
    const int tid = threadIdx.x;                     // 128 threads, 1 block
    const float s = sigma[0] * 8.0f + 16.0f;
    const float inv2v = 1.0f / (2.0f * s * s);
    float sum = 0.0f;
    #pragma unroll
    for (int k = 0; k <= 120; ++k) {
        const float c = (float)k - 60.0f;
        sum += __expf(-c * c * inv2v);
    }
    float g = 0.0f;
    if (tid < 121) {
        const float c = (float)tid - 60.0f;
        g = __expf(-c * c * inv2v);
    }
    wg[tid] = g / sum;               // taps 121..127 exactly 0
}

// dword offset within an LDS row for padded column `col` (swizzled)
__device__ __forceinline__ int swz_off(int col) {
    const int u = col >> 2;
    return ((u ^ ((u >> 3) & 7)) << 2) + (col & 3);
}

// Vertical octet, pipelined: A=X_t (rows base..), B=X_{t+1}; prefetch
// C=X_{t+2} (rows base+16.., clamped) issued BEFORE the FMAs.
#define V_OCT_P(A, B, C, KO)                                              \
    { _Pragma("unroll")                                                   \
      for (int ki = 0; ki < 8; ++ki) {                                    \
          int rr = r0 - 44 + (KO) * 8 + ki;                               \
          rr = rr < 0 ? 0 : (rr > HH - 1 ? HH - 1 : rr);                  \
          C[ki] = *(const float2*)&src[(size_t)rr * WW];                  \
      }                                                                   \
      *(float4*)&wq[0] = *(const float4*)&wg[(KO) * 8];                   \
      *(float4*)&wq[4] = *(const float4*)&wg[(KO) * 8 + 4];               \
      _Pragma("unroll")                                                   \
      for (int ki = 0; ki < 8; ++ki) {                                    \
          const float wk = wq[ki];                                        \
          _Pragma("unroll")                                               \
          for (int j = 0; j < 8; ++j) {                                   \
              const int idx = ki + j;                                     \
              const float2 v = (idx < 8) ? A[idx] : B[idx - 8];           \
              vac[j].x += wk * v.x; vac[j].y += wk * v.y;                 \
          }                                                               \
      }                                                                   \
    }

// Final octet (KO=15): no prefetch; taps 121..127 are zero.
#define V_OCT_NP(A, B, KO)                                                \
    { *(float4*)&wq[0] = *(const float4*)&wg[(KO) * 8];                   \
      *(float4*)&wq[4] = *(const float4*)&wg[(KO) * 8 + 4];               \
      _Pragma("unroll")                                                   \
      for (int ki = 0; ki < 8; ++ki) {                                    \
          const float wk = wq[ki];                                        \
          _Pragma("unroll")                                               \
          for (int j = 0; j < 8; ++j) {                                   \
              const int idx = ki + j;                                     \
              const float2 v = (idx < 8) ? A[idx] : B[idx - 8];           \
              vac[j].x += wk * v.x; vac[j].y += wk * v.y;                 \
          }                                                               \
      }                                                                   \
    }

// Load group G (8 floats): phys(2G+1) = phys(2G)^1 -> one addr calc / 2 b128
#define LOADG(D, G)                                                       \
    { const int u_  = 2 * (G);                                            \
      const int o1_ = (u_ ^ ((u_ >> 3) & 7)) << 2;                        \
      *(float4*)&D[0] = *(const float4*)(bs + o1_);                       \
      *(float4*)&D[4] = *(const float4*)(bs + (o1_ ^ 4)); }

// One octet over a contiguous 16-col span; window A0..A2 (idx<=22), A3 pre.
#define H_OCT16(A0, A1, A2, A3, KO)                                       \
    { LOADG(A3, G0 + (KO) + 3)                                            \
      *(float4*)&wq[0] = *(const float4*)&wg[(KO) * 8];                   \
      *(float4*)&wq[4] = *(const float4*)&wg[(KO) * 8 + 4];               \
      _Pragma("unroll")                                                   \
      for (int ki = 0; ki < 8; ++ki) {                                    \
          const float wk = wq[ki];                                        \
          _Pragma("unroll")                                               \
          for (int j = 0; j < 16; ++j) {                                  \
              const int idx = ki + j;                                     \
              const float v = (idx < 8) ? A0[idx]                         \
                            : (idx < 16) ? A1[idx - 8] : A2[idx - 16];    \
              acc[j] += wk * v;                                           \
          }                                                               \
      }                                                                   \
    }

// Final octet: no prefetch (window = groups G0+15..G0+17, all resident)
#define H_OCT16_NP(A0, A1, A2, A3, KO)                                    \
    { *(float4*)&wq[0] = *(const float4*)&wg[(KO) * 8];                   \
      *(float4*)&wq[4] = *(const float4*)&wg[(KO) * 8 + 4];               \
      _Pragma("unroll")                                                   \
      for (int ki = 0; ki < 8; ++ki) {                                    \
          const float wk = wq[ki];                                        \
          _Pragma("unroll")                                               \
          for (int j = 0; j < 16; ++j) {                                  \
              const int idx = ki + j;                                     \
              const float v = (idx < 8) ? A0[idx]                         \
                            : (idx < 16) ? A1[idx - 8] : A2[idx - 16];    \
              acc[j] += wk * v;                                           \
          }                                                               \
      }                                                                   \
    }

__global__ __launch_bounds__(256, 6) void blur_fused(
        const float* __restrict__ x, const float* __restrict__ wg,
        float* __restrict__ out) {
    __shared__ float sm[8 * ROWF];                   // 21504 B
    const int tid = threadIdx.x;

    // XCD swizzle: linear id -> contiguous 192-tile span per XCD (%8 rr).
    const int lid   = blockIdx.x + gridDim.x * blockIdx.y;   // 0..1535
    const int tile  = (lid & 7) * 192 + (lid >> 3);
    const int r0    = (tile & 63) * 8;               // output rows r0..r0+7
    const int plane = tile >> 6;

    const int c0 = tid * 2;                          // this thread's 2 cols
    const float* __restrict__ src = x + (size_t)plane * PLANE + c0;

    // ---- vertical: 8 rows x 2 cols, 3-buffer load-ahead-by-2 pipeline ----
    float2 w0[8], w1[8], w2[8], vac[8];
    float  wq[8];
    #pragma unroll
    for (int m = 0; m < 8; ++m) {                    // X_0: rows r0-60..r0-53
        int rr = r0 - 60 + m;
        rr = rr < 0 ? 0 : rr;
        w0[m] = *(const float2*)&src[(size_t)rr * WW];
    }
    #pragma unroll
    for (int m = 0; m < 8; ++m) {                    // X_1: rows r0-52..r0-45
        int rr = r0 - 52 + m;
        rr = rr < 0 ? 0 : rr;
        w1[m] = *(const float2*)&src[(size_t)rr * WW];
    }
    #pragma unroll
    for (int j = 0; j < 8; ++j) vac[j] = make_float2(0.f, 0.f);

    #pragma unroll 1
    for (int ko = 0; ko < 15; ko += 3) {             // octets 0..14, period-3
        V_OCT_P(w0, w1, w2, ko)
        V_OCT_P(w1, w2, w0, ko + 1)
        V_OCT_P(w2, w0, w1, ko + 2)
    }
    V_OCT_NP(w0, w1, 15)                             // octet 15, no prefetch

    // write intermediate at halo offset +60 (swizzled; float2 stays in-unit)
    {
        const int off = swz_off(c0 + 60);            // col even -> within-unit
        #pragma unroll
        for (int j = 0; j < 8; ++j)
            *(float2*)&sm[j * ROWF + off] = vac[j];
    }
    __syncthreads();

    // ---- halo: idx 0..59 <- 60; 572..647 <- 571; zero 648..655 -----------
    if (tid < 36) {
        const int p = (tid < 15) ? tid * 4
                    : (tid < 34) ? 572 + (tid - 15) * 4
                                 : 648 + (tid - 34) * 4;
        const int u   = p >> 2;
        const int off = (u ^ ((u >> 3) & 7)) << 2;   // 16B-aligned
        const int soff = (tid < 15) ? swz_off(60) : swz_off(571);
        #pragma unroll
        for (int r8 = 0; r8 < 8; ++r8) {
            const float v = (tid < 34) ? sm[r8 * ROWF + soff] : 0.0f;
            *(float4*)&sm[r8 * ROWF + off] = make_float4(v, v, v, v);
        }
    }
    __syncthreads();

    // ---- horizontal: contiguous 16-col span, PERMUTED assignment ---------
    // lane L computes span sigma(L) = (L>>1) + 16*(L&1):
    //   even L=2m: cols 16m..16m+15; odd L=2m+1: cols 256+16m..+15.
    const int r  = tid >> 5;                         // 0..7
    const int L  = tid & 31;
    const int G0 = (L & 30) + ((L & 1) << 5);        // 2*sigma(L)
    const float* __restrict__ bs = sm + r * ROWF;

    float a0[8], a1[8], a2[8], a3[8];
    float acc[16];
    #pragma unroll
    for (int j = 0; j < 16; ++j) acc[j] = 0.0f;

    LOADG(a0, G0)
    LOADG(a1, G0 + 1)
    LOADG(a2, G0 + 2)

    #pragma unroll 1
    for (int ko = 0; ko < 12; ko += 4) {
        H_OCT16(a0, a1, a2, a3, ko)
        H_OCT16(a1, a2, a3, a0, ko + 1)
        H_OCT16(a2, a3, a0, a1, ko + 2)
        H_OCT16(a3, a0, a1, a2, ko + 3)
    }
    H_OCT16   (a0, a1, a2, a3, 12)
    H_OCT16   (a1, a2, a3, a0, 13)
    H_OCT16   (a2, a3, a0, a1, 14)
    H_OCT16_NP(a3, a0, a1, a2, 15)

    // ---- store: xor-1 exchange -> lane L holds cols 8L..+7, 8L+256..+263 -
    // even L=2m: blkA = own acc[0..7] (16m..+7); blkB = odd partner's
    // acc[0..7] (256+16m..+7). odd L=2m+1: blkA = even partner's acc[8..15]
    // (16m+8..+15); blkB = own acc[8..15] (256+16m+8..+15).
    // Store mapping is byte-for-byte, lane-for-lane identical to R9/R16.
    {
        const int odd = L & 1;
        float blkA[8], blkB[8];
        #pragma unroll
        for (int j = 0; j < 8; ++j) {
            const float send = odd ? acc[j] : acc[8 + j];
            const float recv = __shfl_xor(send, 1, 64);
            blkA[j] = odd ? recv : acc[j];
            blkB[j] = odd ? acc[8 + j] : recv;
        }
        float* __restrict__ dst = out + (size_t)plane * PLANE
                                      + (size_t)(r0 + r) * WW + L * 8;
        *(float4*)(dst)       = make_float4(blkA[0], blkA[1], blkA[2], blkA[3]);
        *(float4*)(dst + 4)   = make_float4(blkA[4], blkA[5], blkA[6], blkA[7]);
        *(float4*)(dst + 256) = make_float4(blkB[0], blkB[1], blkB[2], blkB[3]);
        *(float4*)(dst + 260) = make_float4(blkB[4], blkB[5], blkB[6], blkB[7]);
    }
}

extern "C" void kernel_launch(void* const* d_in, const int* in_sizes, int n_in,
                              void* d_out, int out_size, void* d_ws, size_t ws_size,
                              hipStream_t stream) {
    const float* x     = (const float*)d_in[0];
    const float* sigma = (const float*)d_in[1];
    float* out = (float*)d_out;
    float* wg  = (float*)d_ws;                       // 512 B of workspace
    wk_prep<<<dim3(1), dim3(128), 0, stream>>>(sigma, wg);
    blur_fused<<<dim3(HH / 8, NIMG), dim3(256), 0, stream>>>(x, wg, out);
}

// Round 12
// 114.704 us; speedup vs baseline: 1.1028x; 1.0952x over previous
//
#include <hip/hip_runtime.h>

// Depthwise Gaussian blur K=121, replicate pad, separable, fp32. FUSED.
// R19 = R16 (proven best: 53us, clean traffic) + ROW-PARITY LDS XOR.
// Defect found in R16's H reads: every LOADG2 b128 reads EVEN units only
// (XOR swizzle preserves parity) and row stride 672 dw == 0 mod 32 banks,
// so a wave's two rows hit the SAME 16 even banks -> 16-cycle service vs
// 8-cycle floor = the measured 8.6M conflict cycles (~18 cyc/instr extra,
// ~55K cyc/CU of H LDS-pipe time). Fix: XOR the swizzled unit index with
// (row&1) on BOTH write and read sides (^4 at dword level). Lanes 0-31
// (row r, even phys units) + lanes 32-63 (row r+1, odd phys units) ->
// all 32 banks per instruction. Bijective (XOR<8 stays in octave; 168
// units = 21 exact octaves); preserves phys(2G+1)=phys(2G)^1 and
// phys(u+64)=phys(u)+64. No global-side or register change.
// CLOSED direction: 16-col H span (R10/11/12/17/18 all inflate HBM WRITE
// 2.7-13x regardless of store geometry/lane order; mechanism unknown).
// Kept: 3-buffer load-ahead-2 V phase, scalar pre-normalized weights,
// paired 32B-stride stores, XCD swizzle, launch_bounds(256,6).

#define HH    512
#define WW    512
#define PLANE (512 * 512)
#define NIMG  24
#define ROWF  672                    // 168 16B-units/row, swizzle-bijective

// ---- pre-kernel: 128 normalized 1-D taps -> d_ws --------------------------
__global__ void wk_prep(const float* __restrict__ sigma,
                        float* __restrict__ wg) {
    const int tid = threadIdx.x;                     // 128 threads, 1 block
    const float s = sigma[0] * 8.0f + 16.0f;
    const float inv2v = 1.0f / (2.0f * s * s);
    float sum = 0.0f;
    #pragma unroll
    for (int k = 0; k <= 120; ++k) {
        const float c = (float)k - 60.0f;
        sum += __expf(-c * c * inv2v);
    }
    float g = 0.0f;
    if (tid < 121) {
        const float c = (float)tid - 60.0f;
        g = __expf(-c * c * inv2v);
    }
    wg[tid] = g / sum;               // taps 121..127 exactly 0
}

// dword offset within an LDS row for padded column `col`, parity p=row&1
__device__ __forceinline__ int swz_off(int col) {
    const int u = col >> 2;
    return ((u ^ ((u >> 3) & 7)) << 2) + (col & 3);  // parity-0 form
}

// Vertical octet, pipelined: A=X_t (rows base..), B=X_{t+1}; prefetch
// C=X_{t+2} (rows base+16.., clamped) issued BEFORE the FMAs.
#define V_OCT_P(A, B, C, KO)                                              \
    { _Pragma("unroll")                                                   \
      for (int ki = 0; ki < 8; ++ki) {                                    \
          int rr = r0 - 44 + (KO) * 8 + ki;                               \
          rr = rr < 0 ? 0 : (rr > HH - 1 ? HH - 1 : rr);                  \
          C[ki] = *(const float2*)&src[(size_t)rr * WW];                  \
      }                                                                   \
      *(float4*)&wq[0] = *(const float4*)&wg[(KO) * 8];                   \
      *(float4*)&wq[4] = *(const float4*)&wg[(KO) * 8 + 4];               \
      _Pragma("unroll")                                                   \
      for (int ki = 0; ki < 8; ++ki) {                                    \
          const float wk = wq[ki];                                        \
          _Pragma("unroll")                                               \
          for (int j = 0; j < 8; ++j) {                                   \
              const int idx = ki + j;                                     \
              const float2 v = (idx < 8) ? A[idx] : B[idx - 8];           \
              vac[j].x += wk * v.x; vac[j].y += wk * v.y;                 \
          }                                                               \
      }                                                                   \
    }

// Final octet (KO=15): no prefetch; taps 121..127 are zero.
#define V_OCT_NP(A, B, KO)                                                \
    { *(float4*)&wq[0] = *(const float4*)&wg[(KO) * 8];                   \
      *(float4*)&wq[4] = *(const float4*)&wg[(KO) * 8 + 4];               \
      _Pragma("unroll")                                                   \
      for (int ki = 0; ki < 8; ++ki) {                                    \
          const float wk = wq[ki];                                        \
          _Pragma("unroll")                                               \
          for (int j = 0; j < 8; ++j) {                                   \
              const int idx = ki + j;                                     \
              const float2 v = (idx < 8) ? A[idx] : B[idx - 8];           \
              vac[j].x += wk * v.x; vac[j].y += wk * v.y;                 \
          }                                                               \
      }                                                                   \
    }

// Load group G (span A) and G+32 (span B). parx4 = (row&1)<<2 flips unit
// parity: lanes of row r read even phys units, row r+1 odd -> 32 banks.
#define LOADG2(DA, DB, G)                                                 \
    { const int u_  = 2 * (G);                                            \
      const int o1_ = (((u_ ^ ((u_ >> 3) & 7)) << 2)) ^ parx4;            \
      const int o2_ = o1_ ^ 4;                                            \
      *(float4*)&DA[0] = *(const float4*)(bs + o1_);                      \
      *(float4*)&DA[4] = *(const float4*)(bs + o2_);                      \
      *(float4*)&DB[0] = *(const float4*)(bs + o1_ + 256);                \
      *(float4*)&DB[4] = *(const float4*)(bs + o2_ + 256); }

// One octet, TWO 8-col spans (A: groups L+.., B: groups L+32+..)
#define H_OCT2(A0, A1, A2, A3, B0, B1, B2, B3, KO)                        \
    { LOADG2(A3, B3, L + (KO) + 3)                                        \
      *(float4*)&wq[0] = *(const float4*)&wg[(KO) * 8];                   \
      *(float4*)&wq[4] = *(const float4*)&wg[(KO) * 8 + 4];               \
      _Pragma("unroll")                                                   \
      for (int ki = 0; ki < 8; ++ki) {                                    \
          const float wk = wq[ki];                                        \
          _Pragma("unroll")                                               \
          for (int j = 0; j < 8; ++j) {                                   \
              const int idx = ki + j;                                     \
              const float vA = (idx < 8) ? A0[idx]                        \
                             : (idx < 16) ? A1[idx - 8] : A2[idx - 16];   \
              const float vB = (idx < 8) ? B0[idx]                        \
                             : (idx < 16) ? B1[idx - 8] : B2[idx - 16];   \
              accA[j] += wk * vA;                                         \
              accB[j] += wk * vB;                                         \
          }                                                               \
      }                                                                   \
    }

__global__ __launch_bounds__(256, 6) void blur_fused(
        const float* __restrict__ x, const float* __restrict__ wg,
        float* __restrict__ out) {
    __shared__ float sm[8 * ROWF];                   // 21504 B
    const int tid = threadIdx.x;

    // XCD swizzle: linear id -> contiguous 192-tile span per XCD (%8 rr).
    const int lid   = blockIdx.x + gridDim.x * blockIdx.y;   // 0..1535
    const int tile  = (lid & 7) * 192 + (lid >> 3);
    const int r0    = (tile & 63) * 8;               // output rows r0..r0+7
    const int plane = tile >> 6;

    const int c0 = tid * 2;                          // this thread's 2 cols
    const float* __restrict__ src = x + (size_t)plane * PLANE + c0;

    // ---- vertical: 8 rows x 2 cols, 3-buffer load-ahead-by-2 pipeline ----
    float2 w0[8], w1[8], w2[8], vac[8];
    float  wq[8];
    #pragma unroll
    for (int m = 0; m < 8; ++m) {                    // X_0: rows r0-60..r0-53
        int rr = r0 - 60 + m;
        rr = rr < 0 ? 0 : rr;
        w0[m] = *(const float2*)&src[(size_t)rr * WW];
    }
    #pragma unroll
    for (int m = 0; m < 8; ++m) {                    // X_1: rows r0-52..r0-45
        int rr = r0 - 52 + m;
        rr = rr < 0 ? 0 : rr;
        w1[m] = *(const float2*)&src[(size_t)rr * WW];
    }
    #pragma unroll
    for (int j = 0; j < 8; ++j) vac[j] = make_float2(0.f, 0.f);

    #pragma unroll 1
    for (int ko = 0; ko < 15; ko += 3) {             // octets 0..14, period-3
        V_OCT_P(w0, w1, w2, ko)
        V_OCT_P(w1, w2, w0, ko + 1)
        V_OCT_P(w2, w0, w1, ko + 2)
    }
    V_OCT_NP(w0, w1, 15)                             // octet 15, no prefetch

    // write intermediate at halo offset +60; row-parity XOR (^4 dw if odd)
    {
        const int off = swz_off(c0 + 60);            // parity-0 offset
        #pragma unroll
        for (int j = 0; j < 8; ++j)
            *(float2*)&sm[j * ROWF + (off ^ ((j & 1) << 2))] = vac[j];
    }
    __syncthreads();

    // ---- halo: idx 0..59 <- 60; 572..647 <- 571; zero 648..655 -----------
    if (tid < 36) {
        const int p = (tid < 15) ? tid * 4
                    : (tid < 34) ? 572 + (tid - 15) * 4
                                 : 648 + (tid - 34) * 4;
        const int u    = p >> 2;
        const int off0 = (u ^ ((u >> 3) & 7)) << 2;  // 16B-aligned, parity 0
        const int sof0 = (tid < 15) ? swz_off(60) : swz_off(571);
        #pragma unroll
        for (int r8 = 0; r8 < 8; ++r8) {
            const int pp = (r8 & 1) << 2;
            const float v = (tid < 34) ? sm[r8 * ROWF + (sof0 ^ pp)] : 0.0f;
            *(float4*)&sm[r8 * ROWF + (off0 ^ pp)] = make_float4(v, v, v, v);
        }
    }
    __syncthreads();

    // ---- horizontal: two 8-col spans per lane, rotating 4-octet windows --
    const int r = tid >> 5;                          // 0..7
    const int L = tid & 31;                          // span A cols 8L.., B +256
    const int parx4 = (r & 1) << 2;                  // row-parity unit flip
    const float* __restrict__ bs = sm + r * ROWF;

    float a0[8], a1[8], a2[8], a3[8];
    float b0[8], b1[8], b2[8], b3[8];
    float accA[8], accB[8];
    #pragma unroll
    for (int j = 0; j < 8; ++j) { accA[j] = 0.0f; accB[j] = 0.0f; }

    LOADG2(a0, b0, L)
    LOADG2(a1, b1, L + 1)
    LOADG2(a2, b2, L + 2)

    #pragma unroll 1
    for (int ko = 0; ko < 16; ko += 4) {
        H_OCT2(a0, a1, a2, a3, b0, b1, b2, b3, ko)
        H_OCT2(a1, a2, a3, a0, b1, b2, b3, b0, ko + 1)
        H_OCT2(a2, a3, a0, a1, b2, b3, b0, b1, ko + 2)
        H_OCT2(a3, a0, a1, a2, b3, b0, b1, b2, ko + 3)
    }

    float* __restrict__ dst = out + (size_t)plane * PLANE
                                  + (size_t)(r0 + r) * WW + L * 8;
    *(float4*)(dst)       = make_float4(accA[0], accA[1], accA[2], accA[3]);
    *(float4*)(dst + 4)   = make_float4(accA[4], accA[5], accA[6], accA[7]);
    *(float4*)(dst + 256) = make_float4(accB[0], accB[1], accB[2], accB[3]);
    *(float4*)(dst + 260) = make_float4(accB[4], accB[5], accB[6], accB[7]);
}

extern "C" void kernel_launch(void* const* d_in, const int* in_sizes, int n_in,
                              void* d_out, int out_size, void* d_ws, size_t ws_size,
                              hipStream_t stream) {
    const float* x     = (const float*)d_in[0];
    const float* sigma = (const float*)d_in[1];
    float* out = (float*)d_out;
    float* wg  = (float*)d_ws;                       // 512 B of workspace
    wk_prep<<<dim3(1), dim3(128), 0, stream>>>(sigma, wg);
    blur_fused<<<dim3(HH / 8, NIMG), dim3(256), 0, stream>>>(x, wg, out);
}